// Round 17
// baseline (291.179 us; speedup 1.0000x reference)
//
#include <hip/hip_runtime.h>
#include <hip/hip_bf16.h>

typedef __bf16 bf16;
using bf16x8 = __attribute__((ext_vector_type(8))) __bf16;
using bf16x4 = __attribute__((ext_vector_type(4))) __bf16;
using f32x4  = __attribute__((ext_vector_type(4))) float;
using f32x16 = __attribute__((ext_vector_type(16))) float;

#define DEV __device__ __forceinline__

DEV void load_lds16(const void* g, void* l) {
  __builtin_amdgcn_global_load_lds(
      (const __attribute__((address_space(1))) void*)g,
      (__attribute__((address_space(3))) void*)l, 16, 0, 0);
}

// ---------------- merged preprocessing: f2b(x) + tconv(Wqkv) + tconv(Wout) + invf ------
__global__ __launch_bounds__(256) void k_prep(
    const float* __restrict__ x, bf16* __restrict__ xb,
    const float* __restrict__ Wq, bf16* __restrict__ wqT,
    const float* __restrict__ Wo, bf16* __restrict__ woT,
    float* __restrict__ invf) {
  __shared__ float t[64][65];
  int bid = blockIdx.x;
  int tid = threadIdx.x;
  if (bid < 4096) {                      // f32 -> bf16 convert of x
    long i = ((long)bid * 256 + tid) * 8;
    float4 a = *(const float4*)(x + i);
    float4 b = *(const float4*)(x + i + 4);
    bf16x8 o;
    o[0] = (bf16)a.x; o[1] = (bf16)a.y; o[2] = (bf16)a.z; o[3] = (bf16)a.w;
    o[4] = (bf16)b.x; o[5] = (bf16)b.y; o[6] = (bf16)b.z; o[7] = (bf16)b.w;
    *(bf16x8*)(xb + i) = o;
    return;
  }
  if (bid >= 8192) {                     // RoPE inverse-frequency table
    if (tid < 64) invf[tid] = 1.0f / (float)pow(10000.0, (double)tid / 64.0);
    return;
  }
  const float* in;
  bf16* out;
  int R, C, rb;
  if (bid < 7168) { in = Wq; out = wqT; R = 2048; C = 6144; rb = bid - 4096; }
  else            { in = Wo; out = woT; R = 2048; C = 2048; rb = bid - 7168; }
  int nbc = C >> 6;
  long r0 = (long)(rb / nbc) * 64, c0 = (long)(rb % nbc) * 64;
#pragma unroll
  for (int i = 0; i < 4; ++i) {
    int ch = tid + i * 256;
    int r = ch >> 4, c4 = (ch & 15) * 4;
    float4 v = *(const float4*)(in + (r0 + r) * C + c0 + c4);
    t[r][c4] = v.x; t[r][c4 + 1] = v.y; t[r][c4 + 2] = v.z; t[r][c4 + 3] = v.w;
  }
  __syncthreads();
#pragma unroll
  for (int i = 0; i < 2; ++i) {
    int ch = tid + i * 256;
    int c = ch >> 3, r8 = (ch & 7) * 8;
    bf16x8 o;
#pragma unroll
    for (int j = 0; j < 8; ++j) o[j] = (bf16)t[r8 + j][c];
    *(bf16x8*)(out + (c0 + c) * R + r0 + r8) = o;
  }
}

// ---------------- 8-phase-style 128x256 GEMM, 3-slot ring, exact-round grids -----------
// 8 waves (2M x 4N, 64x64 C each = acc[4][4]). Per K-tile (BK=64): 2 phases of
// { ds_read frags; stage part of tile t+2; s_barrier; lgkmcnt(0); setprio(1) 16 MFMA
//   setprio(0); s_barrier }. 3-slot LDS ring (48 KB/slot, 144 KB) keeps staging 2
// K-tiles ahead; boundary vmcnt(6) (6 loads/tile in flight), vmcnt(0) only at tail.
// fuse=1 (QKV): fused RoPE/RMS epilogue (2 heads per 256-col tile) / V-transpose.
// Grids: QKV 768 = 3 exact CU-rounds; out 256 = 1 exact round (R16's 384 = 1.5 rounds
// cost 25% -- this reparameterization removes the quantization tail).
template <typename OutT>
__global__ __launch_bounds__(512, 1) void k_g8(
    const bf16* __restrict__ A, const bf16* __restrict__ Bt,
    const float* __restrict__ bias, OutT* __restrict__ C,
    int M, int N, int K, int fuse,
    const float* __restrict__ invf,
    const float* __restrict__ qw, const float* __restrict__ kw,
    bf16* __restrict__ q_r, bf16* __restrict__ k_r, bf16* __restrict__ v_t) {
  __shared__ __align__(16) bf16 ls[3 * 8192 + 3 * 16384];  // A slots (16KB) + B slots (32KB)
  bf16* lsA = ls;
  bf16* lsB = ls + 3 * 8192;
  int bid = blockIdx.x;
  { int q = gridDim.x >> 3; bid = (bid & 7) * q + (bid >> 3); }  // XCD swizzle (grid%8==0)
  const int nbm = M >> 7;
  const int bm = bid % nbm, bn = bid / nbm;   // bm fastest: B-panel shared within XCD chunk
  const int tid = threadIdx.x, lane = tid & 63, w = tid >> 6;
  const int wm = w >> 2, wn = w & 3;
  const int fr = lane & 15, fq = lane >> 4;
  const long abase = (long)bm * 128 * K;
  const long bbase = (long)bn * 256 * K;
  const int NT = K >> 6;                      // 32
  f32x4 acc[4][4] = {};
  bf16x8 bfv[4][2];

#define STGA(sl, kt)                                                           \
  { _Pragma("unroll") for (int i2 = 0; i2 < 2; ++i2) {                         \
      int g = i2 * 512 + tid;                                                  \
      int rl = g >> 3, uu = g & 7;                                             \
      load_lds16(A + abase + (long)rl * K + ((kt) << 6) + ((uu ^ (rl & 7)) << 3), \
                 &lsA[(sl) * 8192 + g * 8]); } }
#define STGB(sl, kt, i0, i1)                                                   \
  { _Pragma("unroll") for (int i2 = i0; i2 < i1; ++i2) {                       \
      int g = i2 * 512 + tid;                                                  \
      int rl = g >> 3, uu = g & 7;                                             \
      load_lds16(Bt + bbase + (long)rl * K + ((kt) << 6) + ((uu ^ (rl & 7)) << 3), \
                 &lsB[(sl) * 16384 + g * 8]); } }

  // prologue: tiles 0 (slot0) and 1 (slot1); 6 loads each (A:2, B:4), issue-ordered
  STGA(0, 0) STGB(0, 0, 0, 4)
  STGA(1, 1) STGB(1, 1, 0, 4)

  for (int t = 0; t < NT; ++t) {
    const int sl = t % 3, s2 = (t + 2) % 3;
    if (t < NT - 1) asm volatile("s_waitcnt vmcnt(6)" ::: "memory");
    else            asm volatile("s_waitcnt vmcnt(0)" ::: "memory");
    __builtin_amdgcn_s_barrier();
    // ---- phase 0: m-frags 0,1 + all B-frags; stage A(t+2) + B(t+2) half ----
    {
      bf16x8 af0[2][2];
#pragma unroll
      for (int mm = 0; mm < 2; ++mm)
#pragma unroll
        for (int kk = 0; kk < 2; ++kk) {
          int R = wm * 64 + mm * 16 + fr;
          af0[mm][kk] = *(const bf16x8*)&lsA[sl * 8192 + R * 64 + (((kk * 4 + fq) ^ (R & 7)) << 3)];
        }
#pragma unroll
      for (int nn = 0; nn < 4; ++nn)
#pragma unroll
        for (int kk = 0; kk < 2; ++kk) {
          int R = wn * 64 + nn * 16 + fr;
          bfv[nn][kk] = *(const bf16x8*)&lsB[sl * 16384 + R * 64 + (((kk * 4 + fq) ^ (R & 7)) << 3)];
        }
      if (t + 2 < NT) { STGA(s2, t + 2) STGB(s2, t + 2, 0, 2) }
      __builtin_amdgcn_s_barrier();
      asm volatile("s_waitcnt lgkmcnt(0)" ::: "memory");
      __builtin_amdgcn_s_setprio(1);
#pragma unroll
      for (int mm = 0; mm < 2; ++mm)
#pragma unroll
        for (int nn = 0; nn < 4; ++nn)
#pragma unroll
          for (int kk = 0; kk < 2; ++kk)
            acc[mm][nn] = __builtin_amdgcn_mfma_f32_16x16x32_bf16(af0[mm][kk], bfv[nn][kk],
                                                                  acc[mm][nn], 0, 0, 0);
      __builtin_amdgcn_s_setprio(0);
      __builtin_amdgcn_s_barrier();
    }
    // ---- phase 1: m-frags 2,3 (reuse B-frags); stage B(t+2) second half ----
    {
      bf16x8 af1[2][2];
#pragma unroll
      for (int mm = 0; mm < 2; ++mm)
#pragma unroll
        for (int kk = 0; kk < 2; ++kk) {
          int R = wm * 64 + (2 + mm) * 16 + fr;
          af1[mm][kk] = *(const bf16x8*)&lsA[sl * 8192 + R * 64 + (((kk * 4 + fq) ^ (R & 7)) << 3)];
        }
      if (t + 2 < NT) { STGB(s2, t + 2, 2, 4) }
      __builtin_amdgcn_s_barrier();
      asm volatile("s_waitcnt lgkmcnt(0)" ::: "memory");
      __builtin_amdgcn_s_setprio(1);
#pragma unroll
      for (int mm = 0; mm < 2; ++mm)
#pragma unroll
        for (int nn = 0; nn < 4; ++nn)
#pragma unroll
          for (int kk = 0; kk < 2; ++kk)
            acc[2 + mm][nn] = __builtin_amdgcn_mfma_f32_16x16x32_bf16(af1[mm][kk], bfv[nn][kk],
                                                                      acc[2 + mm][nn], 0, 0, 0);
      __builtin_amdgcn_s_setprio(0);
      __builtin_amdgcn_s_barrier();
    }
  }
#undef STGA
#undef STGB

  if (!fuse) {
#pragma unroll
    for (int nn = 0; nn < 4; ++nn) {
      int col = bn * 256 + wn * 64 + nn * 16 + fr;
      float bv = bias[col];
#pragma unroll
      for (int m = 0; m < 4; ++m) {
        int row0 = bm * 128 + wm * 64 + m * 16 + fq * 4;
#pragma unroll
        for (int r = 0; r < 4; ++r)
          C[(long)(row0 + r) * N + col] = (OutT)(acc[m][nn][r] + bv);
      }
    }
    return;
  }

  // ------------- fused epilogue (QKV: bn 0-7 q / 8-15 k / 16-23 v; 2 heads/tile) -------
  bf16* tile = ls;                       // main loop fully drained (final barrier)
  const int b = bm >> 4, l0 = (bm & 15) << 7;

  if (bn < 16) {
    // q/k: tile[128 row][256 col], col-chunk XOR swizzle
#pragma unroll
    for (int nn = 0; nn < 4; ++nn) {
      int col = wn * 64 + nn * 16 + fr;
      float bv = bias[bn * 256 + col];
#pragma unroll
      for (int m = 0; m < 4; ++m)
#pragma unroll
        for (int r = 0; r < 4; ++r) {
          int row = wm * 64 + m * 16 + fq * 4 + r;
          tile[row * 256 + (col ^ ((row & 7) << 3))] = (bf16)(acc[m][nn][r] + bv);
        }
    }
    __syncthreads();
    const float* wv = (bn < 8) ? qw : kw;
    bf16* dst0 = (bn < 8) ? q_r : k_r;
    const int tc = tid & 15, hh = (tid >> 4) & 1, rgrp = tid >> 5, i8 = tc * 8;
    const int hg = (bn & 7) * 2 + hh;
    const bool lo = i8 < 64;
    float wvv[8], invv[8];
#pragma unroll
    for (int j = 0; j < 8; ++j) wvv[j] = wv[i8 + j];
#pragma unroll
    for (int j = 0; j < 8; ++j) invv[j] = invf[(i8 + j) & 63];
#pragma unroll
    for (int it = 0; it < 8; ++it) {
      int row = it * 16 + rgrp;
      float fl = (float)(l0 + row);
      float cc[8], sn[8];
#pragma unroll
      for (int j = 0; j < 8; ++j) __sincosf(fl * invv[j], &sn[j], &cc[j]);
      int colb = hh * 128 + i8;
      bf16x8 xv = *(const bf16x8*)&tile[row * 256 + (colb ^ ((row & 7) << 3))];
      float v[8], p[8], rr[8];
      float ss = 0.f;
#pragma unroll
      for (int j = 0; j < 8; ++j) v[j] = (float)xv[j];
#pragma unroll
      for (int j = 0; j < 8; ++j) p[j] = __shfl_xor(v[j], 8);  // d <-> d^64 (tc^8)
#pragma unroll
      for (int j = 0; j < 8; ++j) {
        rr[j] = lo ? v[j] * cc[j] - p[j] * sn[j] : v[j] * cc[j] + p[j] * sn[j];
        ss += rr[j] * rr[j];
      }
      ss += __shfl_xor(ss, 1);
      ss += __shfl_xor(ss, 2);
      ss += __shfl_xor(ss, 4);
      ss += __shfl_xor(ss, 8);
      float inv = rsqrtf(ss * (1.f / 128.f) + 1e-6f);
      bf16x8 ov;
#pragma unroll
      for (int j = 0; j < 8; ++j) ov[j] = (bf16)(rr[j] * inv * wvv[j]);
      *(bf16x8*)(dst0 + ((long)((b * 16 + hg) * 2048 + (l0 + row))) * 128 + i8) = ov;
    }
  } else {
    // v: tile transposed [256 col=d][128 row=l], row-chunk XOR swizzle
#pragma unroll
    for (int nn = 0; nn < 4; ++nn) {
      int col = wn * 64 + nn * 16 + fr;
      float bv = bias[bn * 256 + col];
#pragma unroll
      for (int m = 0; m < 4; ++m)
#pragma unroll
        for (int r = 0; r < 4; ++r) {
          int row = wm * 64 + m * 16 + fq * 4 + r;
          tile[col * 128 + (row ^ ((col & 7) << 3))] = (bf16)(acc[m][nn][r] + bv);
        }
    }
    __syncthreads();
#pragma unroll
    for (int it = 0; it < 8; ++it) {
      int ch = it * 512 + tid;          // 4096 chunks of 16 B = [256 d][16 l-chunks]
      int d = ch >> 4, l8 = (ch & 15) * 8;
      int hg = (bn - 16) * 2 + (d >> 7), dl = d & 127;
      bf16x8 vv = *(const bf16x8*)&tile[d * 128 + (l8 ^ ((d & 7) << 3))];
      *(bf16x8*)(v_t + ((long)((b * 16 + hg) * 128 + dl)) * 2048 + l0 + l8) = vv;
    }
  }
}

// ---------------- flash attention v9: T15 double-pipeline (R15-proven) -----------------
__global__ __launch_bounds__(512, 1) void k_attn(
    const bf16* __restrict__ q_r, const bf16* __restrict__ k_r,
    const bf16* __restrict__ v_t, const unsigned char* __restrict__ amask,
    bf16* __restrict__ attno) {
  __shared__ __align__(16) bf16 lK[2][64 * 128];   // [kv][dh], XOR-swizzled (16B chunks)
  __shared__ __align__(16) bf16 lV[3][128 * 64];   // [dh][kv], XOR-swizzled
  __shared__ int sAny;
  const int tid = threadIdx.x, lane = tid & 63, w = tid >> 6;
  const int hi = lane >> 5, q31 = lane & 31;
  const int bh = blockIdx.x & 31, qt = blockIdx.x >> 5;   // head-locality swizzle
  const int b = bh >> 4, h = bh & 15;
  const long hbase = (long)bh * 2048 * 128;
  const int q0 = qt * 256 + w * 32;
  const unsigned char* mb = amask + b * 2048;

  if (tid == 0) sAny = 0;
  __syncthreads();
  {
    unsigned mv = *(const unsigned*)(mb + tid * 4);
    if (mv) sAny = 1;
  }

  bf16x8 qf[8];
#pragma unroll
  for (int ksl = 0; ksl < 8; ++ksl)
    qf[ksl] = *(const bf16x8*)(q_r + hbase + (long)(q0 + q31) * 128 + ksl * 16 + hi * 8);

  f32x16 o[4] = {};
  float m_run = -1e30f, l_run = 0.f;
  const float SC2 = 0.08838834764831845f * 1.4426950408889634f;
  const float L2E = 1.4426950408889634f;

#define STAGE_K(buf, kv0)                                                            \
  {                                                                                  \
    _Pragma("unroll") for (int it = 0; it < 2; ++it) {                               \
      int g = it * 512 + w * 64 + lane;                                              \
      int r = g >> 4, u = g & 15;                                                    \
      load_lds16(k_r + hbase + (long)((kv0) + r) * 128 + ((u ^ (r & 7)) << 3),       \
                 &lK[buf][(it * 512 + w * 64) * 8]);                                 \
    }                                                                                \
  }
#define STAGE_V(buf, kv0)                                                            \
  {                                                                                  \
    _Pragma("unroll") for (int it = 0; it < 2; ++it) {                               \
      int g = it * 512 + w * 64 + lane;                                              \
      int r = g >> 3, u = g & 7;                                                     \
      load_lds16(v_t + hbase + (long)r * 2048 + (kv0) + ((u ^ (r & 7)) << 3),        \
                 &lV[buf][(it * 512 + w * 64) * 8]);                                 \
    }                                                                                \
  }

  STAGE_K(0, 0) STAGE_V(0, 0) STAGE_K(1, 64) STAGE_V(1, 64)
  __syncthreads();
  const bool maskAny = sAny != 0;

  f32x16 st0 = {}, st1 = {};
#pragma unroll
  for (int ksl = 0; ksl < 8; ++ksl) {
    const int u = ksl * 2 + hi;
    bf16x8 kf0 = *(const bf16x8*)&lK[0][q31 * 128 + ((u ^ (q31 & 7)) << 3)];
    bf16x8 kf1 = *(const bf16x8*)&lK[0][(32 + q31) * 128 + ((u ^ (q31 & 7)) << 3)];
    st0 = __builtin_amdgcn_mfma_f32_32x32x16_bf16(kf0, qf[ksl], st0, 0, 0, 0);
    st1 = __builtin_amdgcn_mfma_f32_32x32x16_bf16(kf1, qf[ksl], st1, 0, 0, 0);
  }
  __syncthreads();

  for (int t = 0; t < 32; ++t) {
    const int kv0 = t << 6;
    if (t + 2 < 32) {
      STAGE_K(t & 1, kv0 + 128)
      STAGE_V((t + 2) % 3, kv0 + 128)
    }

    f32x16 sn0 = {}, sn1 = {};
    if (t < 31) {
      const bf16* kb = lK[(t + 1) & 1];
#pragma unroll
      for (int ksl = 0; ksl < 8; ++ksl) {
        const int u = ksl * 2 + hi;
        bf16x8 kf0 = *(const bf16x8*)&kb[q31 * 128 + ((u ^ (q31 & 7)) << 3)];
        bf16x8 kf1 = *(const bf16x8*)&kb[(32 + q31) * 128 + ((u ^ (q31 & 7)) << 3)];
        sn0 = __builtin_amdgcn_mfma_f32_32x32x16_bf16(kf0, qf[ksl], sn0, 0, 0, 0);
        sn1 = __builtin_amdgcn_mfma_f32_32x32x16_bf16(kf1, qf[ksl], sn1, 0, 0, 0);
      }
    }

#pragma unroll
    for (int i = 0; i < 16; ++i) { st0[i] *= SC2; st1[i] *= SC2; }
    if (maskAny) {
#pragma unroll
      for (int i = 0; i < 16; ++i) {
        int c = (i & 3) + 8 * (i >> 2) + 4 * hi;
        if (mb[kv0 + c]) st0[i] += L2E;
        if (mb[kv0 + 32 + c]) st1[i] += L2E;
      }
    }
    float tm = st0[0];
#pragma unroll
    for (int i = 1; i < 16; ++i) tm = fmaxf(tm, st0[i]);
#pragma unroll
    for (int i = 0; i < 16; ++i) tm = fmaxf(tm, st1[i]);
    tm = fmaxf(tm, __shfl_xor(tm, 32));

    if (!__all(tm <= m_run + 8.f)) {
      float mn = fmaxf(m_run, tm);
      float corr = exp2f(m_run - mn);
      m_run = mn;
      l_run *= corr;
#pragma unroll
      for (int i = 0; i < 16; ++i) {
        float cr = __shfl(corr, (i & 3) + 8 * (i >> 2) + 4 * hi);
#pragma unroll
        for (int dt = 0; dt < 4; ++dt) o[dt][i] *= cr;
      }
    }

    float rs = 0.f;
#pragma unroll
    for (int i = 0; i < 16; ++i) { st0[i] = exp2f(st0[i] - m_run); rs += st0[i]; }
#pragma unroll
    for (int i = 0; i < 16; ++i) { st1[i] = exp2f(st1[i] - m_run); rs += st1[i]; }
    rs += __shfl_xor(rs, 32);
    l_run += rs;

    union UU { bf16x4 v; uint2 u; };
    union U8 { bf16x8 v; uint4 u; };
    bf16x8 pa[4];
#define MKPA(pidx, STX, bb)                                                          \
  {                                                                                  \
    UU plo, phi;                                                                     \
    plo.v = (bf16x4){(bf16)STX[bb], (bf16)STX[(bb) + 1], (bf16)STX[(bb) + 2],        \
                     (bf16)STX[(bb) + 3]};                                           \
    phi.v = (bf16x4){(bf16)STX[(bb) + 4], (bf16)STX[(bb) + 5], (bf16)STX[(bb) + 6],  \
                     (bf16)STX[(bb) + 7]};                                           \
    unsigned sx = hi ? plo.u.x : phi.u.x, sy = hi ? plo.u.y : phi.u.y;               \
    unsigned rx = (unsigned)__shfl_xor((int)sx, 32), ry = (unsigned)__shfl_xor((int)sy, 32); \
    U8 f;                                                                            \
    f.u.x = hi ? rx : plo.u.x; f.u.y = hi ? ry : plo.u.y;                            \
    f.u.z = hi ? phi.u.x : rx; f.u.w = hi ? phi.u.y : ry;                            \
    pa[pidx] = f.v;                                                                  \
  }
    MKPA(0, st0, 0) MKPA(1, st0, 8) MKPA(2, st1, 0) MKPA(3, st1, 8)
#undef MKPA

    const bf16* vb3 = lV[t % 3];
#pragma unroll
    for (int dt = 0; dt < 4; ++dt) {
      const int dr = dt * 32 + q31;
#pragma unroll
      for (int ks = 0; ks < 4; ++ks) {
        const int u = ks * 2 + hi;
        bf16x8 vb = *(const bf16x8*)&vb3[dr * 64 + ((u ^ (dr & 7)) << 3)];
        o[dt] = __builtin_amdgcn_mfma_f32_32x32x16_bf16(pa[ks], vb, o[dt], 0, 0, 0);
      }
    }

    __syncthreads();
    st0 = sn0;
    st1 = sn1;
  }
#undef STAGE_K
#undef STAGE_V

  float invl = 1.f / l_run;
#pragma unroll
  for (int i = 0; i < 16; ++i) {
    int q = (i & 3) + 8 * (i >> 2) + 4 * hi;
    int qrow = q0 + q;
    float inv = __shfl(invl, q);
    float zm = inv;
    if (maskAny) { if (mb[qrow]) zm = 0.f; }
#pragma unroll
    for (int dt = 0; dt < 4; ++dt)
      attno[(long)(b * 2048 + qrow) * 2048 + h * 128 + dt * 32 + q31] = (bf16)(o[dt][i] * zm);
  }
}

extern "C" void kernel_launch(void* const* d_in, const int* in_sizes, int n_in,
                              void* d_out, int out_size, void* d_ws, size_t ws_size,
                              hipStream_t stream) {
  const float* x = (const float*)d_in[0];
  const unsigned char* amask = (const unsigned char*)d_in[1];
  const float* Wqkv = (const float*)d_in[2];
  const float* bqkv = (const float*)d_in[3];
  const float* Wout = (const float*)d_in[4];
  const float* bout = (const float*)d_in[5];
  const float* qw = (const float*)d_in[6];
  const float* kw = (const float*)d_in[7];
  float* out = (float*)d_out;
  char* ws = (char*)d_ws;

  bf16* xb   = (bf16*)(ws);                         // 16 MB (reused as attnout later)
  bf16* wqT  = (bf16*)(ws + 16777216);              // 24 MB  Wqkv^T [6144][2048]
  bf16* woT  = (bf16*)(ws + 41943040);              // 8 MB   Wout^T [2048][2048]
  bf16* q_r  = (bf16*)(ws + 100663296);             // 16 MB  [B*H,L,DH]
  bf16* k_r  = (bf16*)(ws + 117440512);             // 16 MB
  bf16* v_t  = (bf16*)(ws + 134217728);             // 16 MB  [B*H,DH,L]
  float* invf = (float*)(ws + 150994944);           // 256 B
  bf16* attno = xb;  // alias: x_bf16 dead after QKV GEMM

  k_prep<<<8193, 256, 0, stream>>>(x, xb, Wqkv, wqT, Wout, woT, invf);
  k_g8<bf16><<<768, 512, 0, stream>>>(xb, wqT, bqkv, (bf16*)nullptr,
                                      4096, 6144, 2048, 1,
                                      invf, qw, kw, q_r, k_r, v_t);
  k_attn<<<256, 512, 0, stream>>>(q_r, k_r, v_t, amask, attno);
  k_g8<float><<<256, 512, 0, stream>>>(attno, woT, bout, out,
                                       4096, 2048, 2048, 0,
                                       nullptr, nullptr, nullptr,
                                       nullptr, nullptr, nullptr);
}

// Round 18
// 289.286 us; speedup vs baseline: 1.0065x; 1.0065x over previous
//
#include <hip/hip_runtime.h>
#include <hip/hip_bf16.h>

typedef __bf16 bf16;
using bf16x8 = __attribute__((ext_vector_type(8))) __bf16;
using bf16x4 = __attribute__((ext_vector_type(4))) __bf16;
using f32x4  = __attribute__((ext_vector_type(4))) float;
using f32x16 = __attribute__((ext_vector_type(16))) float;

#define DEV __device__ __forceinline__

DEV void load_lds16(const void* g, void* l) {
  __builtin_amdgcn_global_load_lds(
      (const __attribute__((address_space(1))) void*)g,
      (__attribute__((address_space(3))) void*)l, 16, 0, 0);
}

// ---------------- merged preprocessing: f2b(x) + tconv(Wqkv) + tconv(Wout) + invf ------
__global__ __launch_bounds__(256) void k_prep(
    const float* __restrict__ x, bf16* __restrict__ xb,
    const float* __restrict__ Wq, bf16* __restrict__ wqT,
    const float* __restrict__ Wo, bf16* __restrict__ woT,
    float* __restrict__ invf) {
  __shared__ float t[64][65];
  int bid = blockIdx.x;
  int tid = threadIdx.x;
  if (bid < 4096) {                      // f32 -> bf16 convert of x
    long i = ((long)bid * 256 + tid) * 8;
    float4 a = *(const float4*)(x + i);
    float4 b = *(const float4*)(x + i + 4);
    bf16x8 o;
    o[0] = (bf16)a.x; o[1] = (bf16)a.y; o[2] = (bf16)a.z; o[3] = (bf16)a.w;
    o[4] = (bf16)b.x; o[5] = (bf16)b.y; o[6] = (bf16)b.z; o[7] = (bf16)b.w;
    *(bf16x8*)(xb + i) = o;
    return;
  }
  if (bid >= 8192) {                     // RoPE inverse-frequency table
    if (tid < 64) invf[tid] = 1.0f / (float)pow(10000.0, (double)tid / 64.0);
    return;
  }
  const float* in;
  bf16* out;
  int R, C, rb;
  if (bid < 7168) { in = Wq; out = wqT; R = 2048; C = 6144; rb = bid - 4096; }
  else            { in = Wo; out = woT; R = 2048; C = 2048; rb = bid - 7168; }
  int nbc = C >> 6;
  long r0 = (long)(rb / nbc) * 64, c0 = (long)(rb % nbc) * 64;
#pragma unroll
  for (int i = 0; i < 4; ++i) {
    int ch = tid + i * 256;
    int r = ch >> 4, c4 = (ch & 15) * 4;
    float4 v = *(const float4*)(in + (r0 + r) * C + c0 + c4);
    t[r][c4] = v.x; t[r][c4 + 1] = v.y; t[r][c4 + 2] = v.z; t[r][c4 + 3] = v.w;
  }
  __syncthreads();
#pragma unroll
  for (int i = 0; i < 2; ++i) {
    int ch = tid + i * 256;
    int c = ch >> 3, r8 = (ch & 7) * 8;
    bf16x8 o;
#pragma unroll
    for (int j = 0; j < 8; ++j) o[j] = (bf16)t[r8 + j][c];
    *(bf16x8*)(out + (c0 + c) * R + r0 + r8) = o;
  }
}

// ---------------- 8-phase 256x256 QKV GEMM + fused RoPE/RMS/V-transpose (R16: 128.5us) --
__global__ __launch_bounds__(512, 1) void k_gemm8q(
    const bf16* __restrict__ A, const bf16* __restrict__ Bt,
    const float* __restrict__ bias,
    const float* __restrict__ invf,
    const float* __restrict__ qw, const float* __restrict__ kw,
    bf16* __restrict__ q_r, bf16* __restrict__ k_r, bf16* __restrict__ v_t) {
  __shared__ __align__(16) bf16 ls[2][2][256 * 64];   // [op A/B][slot][256 rows][64 k]
  int bid = blockIdx.x;
  { int q = gridDim.x >> 3; bid = (bid & 7) * q + (bid >> 3); }  // XCD swizzle (384%8==0)
  const int bm = bid & 15, bn = bid >> 4;   // 16 x 24
  const int tid = threadIdx.x, lane = tid & 63, w = tid >> 6;
  const int wm = w >> 2, wn = w & 3;
  const int fr = lane & 15, fq = lane >> 4;
  const long abase = (long)bm * 256 * 2048;
  const long bbase = (long)bn * 256 * 2048;
  f32x4 acc[8][4] = {};
  bf16x8 bfv[4][2];

#define STG(op, GP, gb, kt, hf)                                                \
  { _Pragma("unroll") for (int it2 = 0; it2 < 2; ++it2) {                      \
      int g = it2 * 512 + tid;                                                 \
      int rl = g >> 3, u = g & 7;                                              \
      load_lds16(GP + gb + (long)((hf) * 128 + rl) * 2048 + ((kt) << 6)        \
                     + ((u ^ (rl & 7)) << 3),                                  \
                 &ls[op][(kt) & 1][(hf) * 8192 + g * 8]);                      \
  } }

#define PH(qd, slot, STGCODE)                                                  \
  {                                                                            \
    bf16x8 afv[2][2];                                                          \
    _Pragma("unroll") for (int mm = 0; mm < 2; ++mm)                           \
      _Pragma("unroll") for (int kk = 0; kk < 2; ++kk) {                       \
        int R = wm * 128 + ((qd) * 2 + mm) * 16 + fr;                          \
        afv[mm][kk] = *(const bf16x8*)&ls[0][slot]                             \
            [R * 64 + (((kk * 4 + fq) ^ (R & 7)) << 3)];                       \
      }                                                                        \
    if ((qd) == 0) {                                                           \
      _Pragma("unroll") for (int nn = 0; nn < 4; ++nn)                         \
        _Pragma("unroll") for (int kk = 0; kk < 2; ++kk) {                     \
          int R = wn * 64 + nn * 16 + fr;                                      \
          bfv[nn][kk] = *(const bf16x8*)&ls[1][slot]                           \
              [R * 64 + (((kk * 4 + fq) ^ (R & 7)) << 3)];                     \
        }                                                                      \
    }                                                                          \
    STGCODE                                                                    \
    __builtin_amdgcn_s_barrier();                                              \
    asm volatile("s_waitcnt lgkmcnt(0)" ::: "memory");                         \
    __builtin_amdgcn_s_setprio(1);                                             \
    _Pragma("unroll") for (int mm = 0; mm < 2; ++mm)                           \
      _Pragma("unroll") for (int nn = 0; nn < 4; ++nn)                         \
        _Pragma("unroll") for (int kk = 0; kk < 2; ++kk)                       \
          acc[(qd) * 2 + mm][nn] = __builtin_amdgcn_mfma_f32_16x16x32_bf16(    \
              afv[mm][kk], bfv[nn][kk], acc[(qd) * 2 + mm][nn], 0, 0, 0);      \
    __builtin_amdgcn_s_setprio(0);                                             \
    __builtin_amdgcn_s_barrier();                                              \
  }

  STG(1, Bt, bbase, 0, 0) STG(1, Bt, bbase, 0, 1)
  STG(0, A, abase, 0, 0)  STG(0, A, abase, 0, 1)
  STG(1, Bt, bbase, 1, 0) STG(1, Bt, bbase, 1, 1)

  for (int u = 0; u < 16; ++u) {
    const int t = 2 * u;
    asm volatile("s_waitcnt vmcnt(4)" ::: "memory");   // K-tile t fully landed
    __builtin_amdgcn_s_barrier();
    PH(0, 0, STG(0, A, abase, t + 1, 0))
    PH(1, 0, STG(0, A, abase, t + 1, 1))
    PH(2, 0, if (u < 15) { STG(1, Bt, bbase, t + 2, 0) })
    PH(3, 0, if (u < 15) { STG(1, Bt, bbase, t + 2, 1) })
    if (u < 15) { asm volatile("s_waitcnt vmcnt(4)" ::: "memory"); }
    else        { asm volatile("s_waitcnt vmcnt(0)" ::: "memory"); }
    __builtin_amdgcn_s_barrier();                      // K-tile t+1 fully landed
    PH(0, 1, if (u < 15) { STG(0, A, abase, t + 2, 0) })
    PH(1, 1, if (u < 15) { STG(0, A, abase, t + 2, 1) })
    PH(2, 1, if (u < 15) { STG(1, Bt, bbase, t + 3, 0) })
    PH(3, 1, if (u < 15) { STG(1, Bt, bbase, t + 3, 1) })
  }
#undef PH
#undef STG

  // ---------------- fused epilogue: tile = [256 rows][256 cols] bf16 in LDS ----------
  bf16* tile = &ls[0][0][0];            // 128 KB, main loop fully drained
  const int b = bm >> 3, l0 = (bm & 7) << 8;

  if (bn < 16) {
#pragma unroll
    for (int n = 0; n < 4; ++n) {
      int col = wn * 64 + n * 16 + fr;
      float bv = bias[bn * 256 + col];
#pragma unroll
      for (int m = 0; m < 8; ++m)
#pragma unroll
        for (int r = 0; r < 4; ++r) {
          int row = wm * 128 + m * 16 + fq * 4 + r;
          tile[row * 256 + (col ^ ((row & 7) << 3))] = (bf16)(acc[m][n][r] + bv);
        }
    }
    __syncthreads();
    const float* wv = (bn < 8) ? qw : kw;
    bf16* dst0 = (bn < 8) ? q_r : k_r;
    const int tc = tid & 15, hh = (tid >> 4) & 1, rgrp = tid >> 5, i8 = tc * 8;
    const int hg = (bn & 7) * 2 + hh;
    const bool lo = i8 < 64;
    float wvv[8], invv[8];
#pragma unroll
    for (int j = 0; j < 8; ++j) wvv[j] = wv[i8 + j];
#pragma unroll
    for (int j = 0; j < 8; ++j) invv[j] = invf[(i8 + j) & 63];
#pragma unroll
    for (int it = 0; it < 16; ++it) {
      int row = it * 16 + rgrp;
      float fl = (float)(l0 + row);
      float cc[8], sn[8];
#pragma unroll
      for (int j = 0; j < 8; ++j) __sincosf(fl * invv[j], &sn[j], &cc[j]);
      int colb = hh * 128 + i8;
      bf16x8 xv = *(const bf16x8*)&tile[row * 256 + (colb ^ ((row & 7) << 3))];
      float v[8], p[8], rr[8];
      float ss = 0.f;
#pragma unroll
      for (int j = 0; j < 8; ++j) v[j] = (float)xv[j];
#pragma unroll
      for (int j = 0; j < 8; ++j) p[j] = __shfl_xor(v[j], 8);  // d <-> d^64 (tc^8)
#pragma unroll
      for (int j = 0; j < 8; ++j) {
        rr[j] = lo ? v[j] * cc[j] - p[j] * sn[j] : v[j] * cc[j] + p[j] * sn[j];
        ss += rr[j] * rr[j];
      }
      ss += __shfl_xor(ss, 1);
      ss += __shfl_xor(ss, 2);
      ss += __shfl_xor(ss, 4);
      ss += __shfl_xor(ss, 8);
      float inv = rsqrtf(ss * (1.f / 128.f) + 1e-6f);
      bf16x8 ov;
#pragma unroll
      for (int j = 0; j < 8; ++j) ov[j] = (bf16)(rr[j] * inv * wvv[j]);
      *(bf16x8*)(dst0 + ((long)((b * 16 + hg) * 2048 + (l0 + row))) * 128 + i8) = ov;
    }
  } else {
#pragma unroll
    for (int n = 0; n < 4; ++n) {
      int col = wn * 64 + n * 16 + fr;
      float bv = bias[bn * 256 + col];
#pragma unroll
      for (int m = 0; m < 8; ++m)
#pragma unroll
        for (int r = 0; r < 4; ++r) {
          int row = wm * 128 + m * 16 + fq * 4 + r;
          tile[col * 256 + (row ^ ((col & 7) << 3))] = (bf16)(acc[m][n][r] + bv);
        }
    }
    __syncthreads();
#pragma unroll
    for (int it = 0; it < 16; ++it) {
      int ch = it * 512 + tid;          // 8192 chunks of 16 B = [256 d][32 l-chunks]
      int d = ch >> 5, l8 = (ch & 31) * 8;
      int hg = (bn - 16) * 2 + (d >> 7), dl = d & 127;
      bf16x8 vv = *(const bf16x8*)&tile[d * 256 + (l8 ^ ((d & 7) << 3))];
      *(bf16x8*)(v_t + ((long)((b * 16 + hg) * 128 + dl)) * 2048 + l0 + l8) = vv;
    }
  }
}

// -------- out-proj GEMM: 128x256 tile, 3-slot ring, 1 exact CU-round (R17-proven) ------
__global__ __launch_bounds__(512, 1) void k_g8out(
    const bf16* __restrict__ A, const bf16* __restrict__ Bt,
    const float* __restrict__ bias, float* __restrict__ C,
    int M, int N, int K) {
  __shared__ __align__(16) bf16 ls[3 * 8192 + 3 * 16384];
  bf16* lsA = ls;
  bf16* lsB = ls + 3 * 8192;
  int bid = blockIdx.x;
  { int q = gridDim.x >> 3; bid = (bid & 7) * q + (bid >> 3); }
  const int nbm = M >> 7;
  const int bm = bid % nbm, bn = bid / nbm;
  const int tid = threadIdx.x, lane = tid & 63, w = tid >> 6;
  const int wm = w >> 2, wn = w & 3;
  const int fr = lane & 15, fq = lane >> 4;
  const long abase = (long)bm * 128 * K;
  const long bbase = (long)bn * 256 * K;
  const int NT = K >> 6;
  f32x4 acc[4][4] = {};
  bf16x8 bfv[4][2];

#define STGA(sl, kt)                                                           \
  { _Pragma("unroll") for (int i2 = 0; i2 < 2; ++i2) {                         \
      int g = i2 * 512 + tid;                                                  \
      int rl = g >> 3, uu = g & 7;                                             \
      load_lds16(A + abase + (long)rl * K + ((kt) << 6) + ((uu ^ (rl & 7)) << 3), \
                 &lsA[(sl) * 8192 + g * 8]); } }
#define STGB(sl, kt, i0, i1)                                                   \
  { _Pragma("unroll") for (int i2 = i0; i2 < i1; ++i2) {                       \
      int g = i2 * 512 + tid;                                                  \
      int rl = g >> 3, uu = g & 7;                                             \
      load_lds16(Bt + bbase + (long)rl * K + ((kt) << 6) + ((uu ^ (rl & 7)) << 3), \
                 &lsB[(sl) * 16384 + g * 8]); } }

  STGA(0, 0) STGB(0, 0, 0, 4)
  STGA(1, 1) STGB(1, 1, 0, 4)

  for (int t = 0; t < NT; ++t) {
    const int sl = t % 3, s2 = (t + 2) % 3;
    if (t < NT - 1) asm volatile("s_waitcnt vmcnt(6)" ::: "memory");
    else            asm volatile("s_waitcnt vmcnt(0)" ::: "memory");
    __builtin_amdgcn_s_barrier();
    {
      bf16x8 af0[2][2];
#pragma unroll
      for (int mm = 0; mm < 2; ++mm)
#pragma unroll
        for (int kk = 0; kk < 2; ++kk) {
          int R = wm * 64 + mm * 16 + fr;
          af0[mm][kk] = *(const bf16x8*)&lsA[sl * 8192 + R * 64 + (((kk * 4 + fq) ^ (R & 7)) << 3)];
        }
#pragma unroll
      for (int nn = 0; nn < 4; ++nn)
#pragma unroll
        for (int kk = 0; kk < 2; ++kk) {
          int R = wn * 64 + nn * 16 + fr;
          bfv[nn][kk] = *(const bf16x8*)&lsB[sl * 16384 + R * 64 + (((kk * 4 + fq) ^ (R & 7)) << 3)];
        }
      if (t + 2 < NT) { STGA(s2, t + 2) STGB(s2, t + 2, 0, 2) }
      __builtin_amdgcn_s_barrier();
      asm volatile("s_waitcnt lgkmcnt(0)" ::: "memory");
      __builtin_amdgcn_s_setprio(1);
#pragma unroll
      for (int mm = 0; mm < 2; ++mm)
#pragma unroll
        for (int nn = 0; nn < 4; ++nn)
#pragma unroll
          for (int kk = 0; kk < 2; ++kk)
            acc[mm][nn] = __builtin_amdgcn_mfma_f32_16x16x32_bf16(af0[mm][kk], bfv[nn][kk],
                                                                  acc[mm][nn], 0, 0, 0);
      __builtin_amdgcn_s_setprio(0);
      __builtin_amdgcn_s_barrier();
    }
    {
      bf16x8 af1[2][2];
#pragma unroll
      for (int mm = 0; mm < 2; ++mm)
#pragma unroll
        for (int kk = 0; kk < 2; ++kk) {
          int R = wm * 64 + (2 + mm) * 16 + fr;
          af1[mm][kk] = *(const bf16x8*)&lsA[sl * 8192 + R * 64 + (((kk * 4 + fq) ^ (R & 7)) << 3)];
        }
      if (t + 2 < NT) { STGB(s2, t + 2, 2, 4) }
      __builtin_amdgcn_s_barrier();
      asm volatile("s_waitcnt lgkmcnt(0)" ::: "memory");
      __builtin_amdgcn_s_setprio(1);
#pragma unroll
      for (int mm = 0; mm < 2; ++mm)
#pragma unroll
        for (int nn = 0; nn < 4; ++nn)
#pragma unroll
          for (int kk = 0; kk < 2; ++kk)
            acc[2 + mm][nn] = __builtin_amdgcn_mfma_f32_16x16x32_bf16(af1[mm][kk], bfv[nn][kk],
                                                                      acc[2 + mm][nn], 0, 0, 0);
      __builtin_amdgcn_s_setprio(0);
      __builtin_amdgcn_s_barrier();
    }
  }
#undef STGA
#undef STGB

#pragma unroll
  for (int nn = 0; nn < 4; ++nn) {
    int col = bn * 256 + wn * 64 + nn * 16 + fr;
    float bv = bias[col];
#pragma unroll
    for (int m = 0; m < 4; ++m) {
      int row0 = bm * 128 + wm * 64 + m * 16 + fq * 4;
#pragma unroll
      for (int r = 0; r < 4; ++r)
        C[(long)(row0 + r) * N + col] = acc[m][nn][r] + bv;
    }
  }
}

// ---------------- flash attention v9: T15 double-pipeline (R15-proven) -----------------
__global__ __launch_bounds__(512, 1) void k_attn(
    const bf16* __restrict__ q_r, const bf16* __restrict__ k_r,
    const bf16* __restrict__ v_t, const unsigned char* __restrict__ amask,
    bf16* __restrict__ attno) {
  __shared__ __align__(16) bf16 lK[2][64 * 128];   // [kv][dh], XOR-swizzled (16B chunks)
  __shared__ __align__(16) bf16 lV[3][128 * 64];   // [dh][kv], XOR-swizzled
  __shared__ int sAny;
  const int tid = threadIdx.x, lane = tid & 63, w = tid >> 6;
  const int hi = lane >> 5, q31 = lane & 31;
  const int bh = blockIdx.x & 31, qt = blockIdx.x >> 5;   // head-locality swizzle
  const int b = bh >> 4, h = bh & 15;
  const long hbase = (long)bh * 2048 * 128;
  const int q0 = qt * 256 + w * 32;
  const unsigned char* mb = amask + b * 2048;

  if (tid == 0) sAny = 0;
  __syncthreads();
  {
    unsigned mv = *(const unsigned*)(mb + tid * 4);
    if (mv) sAny = 1;
  }

  bf16x8 qf[8];
#pragma unroll
  for (int ksl = 0; ksl < 8; ++ksl)
    qf[ksl] = *(const bf16x8*)(q_r + hbase + (long)(q0 + q31) * 128 + ksl * 16 + hi * 8);

  f32x16 o[4] = {};
  float m_run = -1e30f, l_run = 0.f;
  const float SC2 = 0.08838834764831845f * 1.4426950408889634f;
  const float L2E = 1.4426950408889634f;

#define STAGE_K(buf, kv0)                                                            \
  {                                                                                  \
    _Pragma("unroll") for (int it = 0; it < 2; ++it) {                               \
      int g = it * 512 + w * 64 + lane;                                              \
      int r = g >> 4, u = g & 15;                                                    \
      load_lds16(k_r + hbase + (long)((kv0) + r) * 128 + ((u ^ (r & 7)) << 3),       \
                 &lK[buf][(it * 512 + w * 64) * 8]);                                 \
    }                                                                                \
  }
#define STAGE_V(buf, kv0)                                                            \
  {                                                                                  \
    _Pragma("unroll") for (int it = 0; it < 2; ++it) {                               \
      int g = it * 512 + w * 64 + lane;                                              \
      int r = g >> 3, u = g & 7;                                                     \
      load_lds16(v_t + hbase + (long)r * 2048 + (kv0) + ((u ^ (r & 7)) << 3),        \
                 &lV[buf][(it * 512 + w * 64) * 8]);                                 \
    }                                                                                \
  }

  STAGE_K(0, 0) STAGE_V(0, 0) STAGE_K(1, 64) STAGE_V(1, 64)
  __syncthreads();
  const bool maskAny = sAny != 0;

  f32x16 st0 = {}, st1 = {};
#pragma unroll
  for (int ksl = 0; ksl < 8; ++ksl) {
    const int u = ksl * 2 + hi;
    bf16x8 kf0 = *(const bf16x8*)&lK[0][q31 * 128 + ((u ^ (q31 & 7)) << 3)];
    bf16x8 kf1 = *(const bf16x8*)&lK[0][(32 + q31) * 128 + ((u ^ (q31 & 7)) << 3)];
    st0 = __builtin_amdgcn_mfma_f32_32x32x16_bf16(kf0, qf[ksl], st0, 0, 0, 0);
    st1 = __builtin_amdgcn_mfma_f32_32x32x16_bf16(kf1, qf[ksl], st1, 0, 0, 0);
  }
  __syncthreads();

  for (int t = 0; t < 32; ++t) {
    const int kv0 = t << 6;
    if (t + 2 < 32) {
      STAGE_K(t & 1, kv0 + 128)
      STAGE_V((t + 2) % 3, kv0 + 128)
    }

    f32x16 sn0 = {}, sn1 = {};
    if (t < 31) {
      const bf16* kb = lK[(t + 1) & 1];
#pragma unroll
      for (int ksl = 0; ksl < 8; ++ksl) {
        const int u = ksl * 2 + hi;
        bf16x8 kf0 = *(const bf16x8*)&kb[q31 * 128 + ((u ^ (q31 & 7)) << 3)];
        bf16x8 kf1 = *(const bf16x8*)&kb[(32 + q31) * 128 + ((u ^ (q31 & 7)) << 3)];
        sn0 = __builtin_amdgcn_mfma_f32_32x32x16_bf16(kf0, qf[ksl], sn0, 0, 0, 0);
        sn1 = __builtin_amdgcn_mfma_f32_32x32x16_bf16(kf1, qf[ksl], sn1, 0, 0, 0);
      }
    }

#pragma unroll
    for (int i = 0; i < 16; ++i) { st0[i] *= SC2; st1[i] *= SC2; }
    if (maskAny) {
#pragma unroll
      for (int i = 0; i < 16; ++i) {
        int c = (i & 3) + 8 * (i >> 2) + 4 * hi;
        if (mb[kv0 + c]) st0[i] += L2E;
        if (mb[kv0 + 32 + c]) st1[i] += L2E;
      }
    }
    float tm = st0[0];
#pragma unroll
    for (int i = 1; i < 16; ++i) tm = fmaxf(tm, st0[i]);
#pragma unroll
    for (int i = 0; i < 16; ++i) tm = fmaxf(tm, st1[i]);
    tm = fmaxf(tm, __shfl_xor(tm, 32));

    if (!__all(tm <= m_run + 8.f)) {
      float mn = fmaxf(m_run, tm);
      float corr = exp2f(m_run - mn);
      m_run = mn;
      l_run *= corr;
#pragma unroll
      for (int i = 0; i < 16; ++i) {
        float cr = __shfl(corr, (i & 3) + 8 * (i >> 2) + 4 * hi);
#pragma unroll
        for (int dt = 0; dt < 4; ++dt) o[dt][i] *= cr;
      }
    }

    float rs = 0.f;
#pragma unroll
    for (int i = 0; i < 16; ++i) { st0[i] = exp2f(st0[i] - m_run); rs += st0[i]; }
#pragma unroll
    for (int i = 0; i < 16; ++i) { st1[i] = exp2f(st1[i] - m_run); rs += st1[i]; }
    rs += __shfl_xor(rs, 32);
    l_run += rs;

    union UU { bf16x4 v; uint2 u; };
    union U8 { bf16x8 v; uint4 u; };
    bf16x8 pa[4];
#define MKPA(pidx, STX, bb)                                                          \
  {                                                                                  \
    UU plo, phi;                                                                     \
    plo.v = (bf16x4){(bf16)STX[bb], (bf16)STX[(bb) + 1], (bf16)STX[(bb) + 2],        \
                     (bf16)STX[(bb) + 3]};                                           \
    phi.v = (bf16x4){(bf16)STX[(bb) + 4], (bf16)STX[(bb) + 5], (bf16)STX[(bb) + 6],  \
                     (bf16)STX[(bb) + 7]};                                           \
    unsigned sx = hi ? plo.u.x : phi.u.x, sy = hi ? plo.u.y : phi.u.y;               \
    unsigned rx = (unsigned)__shfl_xor((int)sx, 32), ry = (unsigned)__shfl_xor((int)sy, 32); \
    U8 f;                                                                            \
    f.u.x = hi ? rx : plo.u.x; f.u.y = hi ? ry : plo.u.y;                            \
    f.u.z = hi ? phi.u.x : rx; f.u.w = hi ? phi.u.y : ry;                            \
    pa[pidx] = f.v;                                                                  \
  }
    MKPA(0, st0, 0) MKPA(1, st0, 8) MKPA(2, st1, 0) MKPA(3, st1, 8)
#undef MKPA

    const bf16* vb3 = lV[t % 3];
#pragma unroll
    for (int dt = 0; dt < 4; ++dt) {
      const int dr = dt * 32 + q31;
#pragma unroll
      for (int ks = 0; ks < 4; ++ks) {
        const int u = ks * 2 + hi;
        bf16x8 vb = *(const bf16x8*)&vb3[dr * 64 + ((u ^ (dr & 7)) << 3)];
        o[dt] = __builtin_amdgcn_mfma_f32_32x32x16_bf16(pa[ks], vb, o[dt], 0, 0, 0);
      }
    }

    __syncthreads();
    st0 = sn0;
    st1 = sn1;
  }
#undef STAGE_K
#undef STAGE_V

  float invl = 1.f / l_run;
#pragma unroll
  for (int i = 0; i < 16; ++i) {
    int q = (i & 3) + 8 * (i >> 2) + 4 * hi;
    int qrow = q0 + q;
    float inv = __shfl(invl, q);
    float zm = inv;
    if (maskAny) { if (mb[qrow]) zm = 0.f; }
#pragma unroll
    for (int dt = 0; dt < 4; ++dt)
      attno[(long)(b * 2048 + qrow) * 2048 + h * 128 + dt * 32 + q31] = (bf16)(o[dt][i] * zm);
  }
}

extern "C" void kernel_launch(void* const* d_in, const int* in_sizes, int n_in,
                              void* d_out, int out_size, void* d_ws, size_t ws_size,
                              hipStream_t stream) {
  const float* x = (const float*)d_in[0];
  const unsigned char* amask = (const unsigned char*)d_in[1];
  const float* Wqkv = (const float*)d_in[2];
  const float* bqkv = (const float*)d_in[3];
  const float* Wout = (const float*)d_in[4];
  const float* bout = (const float*)d_in[5];
  const float* qw = (const float*)d_in[6];
  const float* kw = (const float*)d_in[7];
  float* out = (float*)d_out;
  char* ws = (char*)d_ws;

  bf16* xb   = (bf16*)(ws);                         // 16 MB (reused as attnout later)
  bf16* wqT  = (bf16*)(ws + 16777216);              // 24 MB  Wqkv^T [6144][2048]
  bf16* woT  = (bf16*)(ws + 41943040);              // 8 MB   Wout^T [2048][2048]
  bf16* q_r  = (bf16*)(ws + 100663296);             // 16 MB  [B*H,L,DH]
  bf16* k_r  = (bf16*)(ws + 117440512);             // 16 MB
  bf16* v_t  = (bf16*)(ws + 134217728);             // 16 MB  [B*H,DH,L]
  float* invf = (float*)(ws + 150994944);           // 256 B
  bf16* attno = xb;  // alias: x_bf16 dead after QKV GEMM

  k_prep<<<8193, 256, 0, stream>>>(x, xb, Wqkv, wqT, Wout, woT, invf);
  k_gemm8q<<<384, 512, 0, stream>>>(xb, wqT, bqkv, invf, qw, kw, q_r, k_r, v_t);
  k_attn<<<256, 512, 0, stream>>>(q_r, k_r, v_t, amask, attno);
  k_g8out<<<256, 512, 0, stream>>>(attno, woT, bout, out, 4096, 2048, 2048);
}